// Round 5
// baseline (265.581 us; speedup 1.0000x reference)
//
#include <hip/hip_runtime.h>

// Node_GCN: out[n,j,h] = FF_f(x)[n,j,h] + sum_i edge[n,i,j] * FF_g(cat(x,x))[n,i,h]
// fp32 globals, bf16 MFMA internals (abs threshold 9.56 >> bf16 error ~2).
// N=8, m=2048, D_IN=64, H=128.
//
//   k_gx  : gxF = sender MLP output, stored in MFMA B-FRAGMENT ORDER:
//           gxF[batch][kk][hb][ks][lane][8] -> k_main B-load = base + l*16B, coalesced.
//           v6: weight staging vectorized (f32x4, 24 loads/thread vs 96 scalar).
//   k_main: out[n,j,h] = edge^T @ gx + self_MLP(x_j)   fused, pure store (no RMW)
//           v6: 1024 blocks (4/CU, 16 waves/CU), tile 16j x 128h, K=2048 in BK=64.
//           = v3 occupancy x v4 coalesced fragment loads x v5 relaxed barriers.
//           Waves split h 4-ways (dup-free gx). eT double-buffered, 1 LDS-only
//           barrier/step (lgkmcnt(0)+s_barrier; register prefetches stay in flight,
//           compiler emits counted vmcnt at first use). Edge prefetch dist 2,
//           gx dist 1. setprio(1) around MFMA cluster.

typedef __attribute__((ext_vector_type(8))) short bf16x8;
typedef __attribute__((ext_vector_type(4))) unsigned short u16x4;
typedef __attribute__((ext_vector_type(4))) float f32x4;

static __device__ __forceinline__ unsigned short f2bf(float f) {
  union { float f; unsigned int i; } c; c.f = f;
  return (unsigned short)((c.i + 0x7fffu + ((c.i >> 16) & 1u)) >> 16);
}

// LDS-only barrier: make this wave's ds_writes visible, sync, do NOT drain vmcnt.
#define LBAR() do { \
  asm volatile("s_waitcnt lgkmcnt(0)" ::: "memory"); \
  __builtin_amdgcn_s_barrier(); \
} while (0)

// ---------------- k_gx: sender MLP, fragment-ordered bf16 store (64 rows/block, 4 waves) ----------------
__global__ __launch_bounds__(256) void k_gx(
    const float* __restrict__ x,
    const float* __restrict__ gw1,
    const float* __restrict__ gb1,
    const float* __restrict__ gw2,
    const float* __restrict__ gb2,
    unsigned short* __restrict__ gxF)
{
  __shared__ short xs[64 * 64];     // 8 KB
  __shared__ short w1T[128 * 64];   // 16 KB  folded gw1' transposed [n][k], k<64
  __shared__ short w2T[128 * 128];  // 32 KB  gw2T [n][k], k<128
  __shared__ short h2s[64 * 128];   // 16 KB

  const int t = threadIdx.x;
  const int R0 = blockIdx.x * 64;

  // vectorized weight staging: f32x4 global loads (n is the minor dim of gw1/gw2)
  for (int idx4 = t; idx4 < 64 * 32; idx4 += 256) {   // gw1: k<64, n<128
    int k = idx4 >> 5, n0 = (idx4 & 31) << 2;
    f32x4 v1 = *(const f32x4*)(gw1 + (idx4 << 2));
    f32x4 v2 = *(const f32x4*)(gw1 + 64 * 128 + (idx4 << 2));  // fold cat(x,x)
#pragma unroll
    for (int r = 0; r < 4; ++r) {
      int n = n0 + r;
      w1T[(n << 6) + (((k >> 3) ^ (n & 7)) << 3) + (k & 7)] = (short)f2bf(v1[r] + v2[r]);
    }
  }
  for (int idx4 = t; idx4 < 128 * 32; idx4 += 256) {  // gw2: k<128, n<128
    int k = idx4 >> 5, n0 = (idx4 & 31) << 2;
    f32x4 v = *(const f32x4*)(gw2 + (idx4 << 2));
#pragma unroll
    for (int r = 0; r < 4; ++r) {
      int n = n0 + r;
      w2T[(n << 7) + (((k >> 3) ^ (n & 7)) << 3) + (k & 7)] = (short)f2bf(v[r]);
    }
  }
  for (int s = t; s < 64 * 16; s += 256) {
    int row = s >> 4, c4 = s & 15;
    f32x4 v = *(const f32x4*)(x + (size_t)(R0 + row) * 64 + c4 * 4);
    u16x4 pk;
#pragma unroll
    for (int r = 0; r < 4; ++r) pk[r] = f2bf(v[r]);
    *(u16x4*)(xs + (row << 6) + (((c4 >> 1) ^ (row & 7)) << 3) + ((c4 & 1) << 2)) = pk;
  }
  __syncthreads();

  const int w = t >> 6, l = t & 63;
  const int lr = l & 15, q = l >> 4;
  const int mrow = w * 16 + lr;

  bf16x8 a[2];
#pragma unroll
  for (int ks = 0; ks < 2; ++ks) {
    int c = ks * 4 + q;
    a[ks] = *(const bf16x8*)(xs + (mrow << 6) + ((c ^ (mrow & 7)) << 3));
  }

  f32x4 acc;
#pragma unroll
  for (int nf = 0; nf < 8; ++nf) {
    acc = (f32x4){0.f, 0.f, 0.f, 0.f};
#pragma unroll
    for (int ks = 0; ks < 2; ++ks) {
      int c = ks * 4 + q;
      int nr = nf * 16 + lr;
      bf16x8 b = *(const bf16x8*)(w1T + (nr << 6) + ((c ^ (nr & 7)) << 3));
      acc = __builtin_amdgcn_mfma_f32_16x16x32_bf16(a[ks], b, acc, 0, 0, 0);
    }
    float bias = gb1[nf * 16 + lr];
#pragma unroll
    for (int r = 0; r < 4; ++r) {
      float v = acc[r] + bias;
      v = v > 0.f ? v : 0.f;
      int row = w * 16 + q * 4 + r, n = nf * 16 + lr;
      h2s[(row << 7) + (((n >> 3) ^ (row & 7)) << 3) + (n & 7)] = (short)f2bf(v);
    }
  }
  __syncthreads();

  bf16x8 a2[4];
#pragma unroll
  for (int ks = 0; ks < 4; ++ks) {
    int c = ks * 4 + q;
    a2[ks] = *(const bf16x8*)(h2s + (mrow << 7) + ((c ^ (mrow & 7)) << 3));
  }
  // fragment-ordered store: this lane holds rows i = R0 + w*16 + q*4 + 0..3, col h = nf*16+lr.
  const int batch = R0 >> 11;
  const int kk = (R0 & 2047) >> 6;
  unsigned short* gbase = gxF + (size_t)batch * (128 * 2048) + (size_t)kk * (128 * 64);
  const int cch = w * 2 + (q >> 1);
  const int ks2 = cch >> 2, qq = cch & 3, r8 = (q & 1) * 4;
#pragma unroll
  for (int nf = 0; nf < 8; ++nf) {
    acc = (f32x4){0.f, 0.f, 0.f, 0.f};
#pragma unroll
    for (int ks = 0; ks < 4; ++ks) {
      int c = ks * 4 + q;
      int nr = nf * 16 + lr;
      bf16x8 b = *(const bf16x8*)(w2T + (nr << 7) + ((c ^ (nr & 7)) << 3));
      acc = __builtin_amdgcn_mfma_f32_16x16x32_bf16(a2[ks], b, acc, 0, 0, 0);
    }
    float bias = gb2[nf * 16 + lr];
    u16x4 pk;
#pragma unroll
    for (int r = 0; r < 4; ++r) pk[r] = f2bf(acc[r] + bias);
    *(u16x4*)(gbase + (((nf * 2 + ks2) * 64 + qq * 16 + lr) << 3) + r8) = pk;
  }
}

// ---------------- k_main: fused einsum + self-MLP ----------------
__global__ __launch_bounds__(256, 4) void k_main(
    const float* __restrict__ edge,
    const unsigned short* __restrict__ gxF,
    const float* __restrict__ x,
    const float* __restrict__ fw1,
    const float* __restrict__ fb1,
    const float* __restrict__ fw2,
    const float* __restrict__ fb2,
    float* __restrict__ out)
{
  // eT[buf][jj 0..15][ii 0..63]: stride 72 shorts, chunk swizzle (ii>>3)^(jj>>3).
  // gx B-fragments read straight from global in fragment order (coalesced 16B/lane).
  __shared__ short eT[2][16 * 72]; // 4.5 KB double-buffered edge^T tile
  __shared__ short bT[128 * 64];   // 16 KB (epilogue: fw2T)
  __shared__ short xs[16 * 64];    // 2 KB  (epilogue)
  __shared__ short w1T[64 * 64];   // 8 KB  (epilogue)
  __shared__ short h1s[16 * 64];   // 2 KB  (epilogue)   total ~33 KB -> 4 blocks/CU

  const int t = threadIdx.x;
  const int batch = blockIdx.x & 7;   // XCD-pinned: each XCD sees one batch's gx (512 KB)
  const int j0 = (blockIdx.x >> 3) * 16;

  const int w = t >> 6, l = t & 63;   // wave w owns h-range [w*32, w*32+32)
  const int lr = l & 15, q = l >> 4;

  // edge loader roles: 256 threads cover 64i x 16j fp32 tile, one f32x4 each
  const int e_ii = t >> 2;          // 0..63
  const int e_cj = t & 3;           // 0..3  (4 j each)

  const float* ep = edge + (size_t)batch * 2048 * 2048 + (size_t)e_ii * 2048 + j0 + e_cj * 4;
  // fragment-order gx base: wave w owns h-blocks hb = w*2 + nf (nf<2)
  const unsigned short* gp = gxF + (size_t)batch * (128 * 2048) + w * 2048 + (size_t)l * 8;

  f32x4 acc[2];
#pragma unroll
  for (int nf = 0; nf < 2; ++nf) acc[nf] = (f32x4){0.f, 0.f, 0.f, 0.f};

  // ---- helpers (all indices static after unroll) ----
  auto lde = [&](int kk, f32x4& er) {
    er = *(const f32x4*)(ep + (size_t)kk * 64 * 2048);
  };
  auto ldg = [&](int kk, bf16x8 gf[4]) {  // 4 coalesced 16B/lane loads (1 KB/wave each)
    const unsigned short* p = gp + kk * 8192;
#pragma unroll
    for (int nf = 0; nf < 2; ++nf)
#pragma unroll
      for (int ks = 0; ks < 2; ++ks)
        gf[nf * 2 + ks] = *(const bf16x8*)(p + nf * 1024 + ks * 512);
  };
  auto st_e = [&](int buf, const f32x4& er) {
#pragma unroll
    for (int u = 0; u < 4; ++u) {
      int jj = e_cj * 4 + u;
      eT[buf][jj * 72 + (((e_ii >> 3) ^ (jj >> 3)) << 3) + (e_ii & 7)] = (short)f2bf(er[u]);
    }
  };
  auto comp = [&](int buf, const bf16x8 gf[4]) {
    __builtin_amdgcn_s_setprio(1);
#pragma unroll
    for (int ks = 0; ks < 2; ++ks) {
      const int c = ks * 4 + q;
      bf16x8 a = *(const bf16x8*)(&eT[buf][lr * 72 + ((c ^ (lr >> 3)) << 3)]);
#pragma unroll
      for (int nf = 0; nf < 2; ++nf)
        acc[nf] = __builtin_amdgcn_mfma_f32_16x16x32_bf16(a, gf[nf * 2 + ks], acc[nf], 0, 0, 0);
    }
    __builtin_amdgcn_s_setprio(0);
  };

  // ---- main K loop: 32 tiles, 2x unrolled, eT double-buffered, 1 LDS-barrier/step ----
  f32x4 erA, erB;
  bf16x8 gfA[4], gfB[4];

  lde(0, erA);
  ldg(0, gfA);
  lde(1, erB);
  st_e(0, erA);
  LBAR();              // gfA, erB stay in flight

#pragma unroll 1
  for (int mm = 0; mm < 15; ++mm) {
    // step 2mm: read eT0 + gfA
    ldg(2 * mm + 1, gfB);
    lde(2 * mm + 2, erA);
    comp(0, gfA);      // counted vmcnt for gfA, not 0
    st_e(1, erB);      // eT for step 2mm+1 (erB loaded a full step ago)
    LBAR();
    // step 2mm+1: read eT1 + gfB
    ldg(2 * mm + 2, gfA);
    lde(2 * mm + 3, erB);
    comp(1, gfB);
    st_e(0, erA);      // eT for step 2mm+2
    LBAR();
  }
  // tail: steps 30, 31
  ldg(31, gfB);
  comp(0, gfA);        // step 30
  st_e(1, erB);
  LBAR();
  comp(1, gfB);        // step 31

  // ---- fused self-MLP epilogue: acc += relu(x_j @ fw1 + b1) @ fw2 + b2 ----
  for (int idx = t; idx < 64 * 64; idx += 256) {
    int k = idx >> 6, n = idx & 63;  // fw1[k][n]
    w1T[(n << 6) + (((k >> 3) ^ (n & 7)) << 3) + (k & 7)] = (short)f2bf(fw1[idx]);
  }
  for (int idx = t; idx < 64 * 128; idx += 256) {
    int k = idx >> 7, n = idx & 127;  // fw2[k][n] -> bT as fw2T
    bT[(n << 6) + (((k >> 3) ^ (n & 7)) << 3) + (k & 7)] = (short)f2bf(fw2[idx]);
  }
  {
    int s = t;  // 16 rows x 16 f32x4-chunks = 256 threads, one each
    int row = s >> 4, c4 = s & 15;
    f32x4 v = *(const f32x4*)(x + (size_t)(batch * 2048 + j0 + row) * 64 + c4 * 4);
    u16x4 pk;
#pragma unroll
    for (int r = 0; r < 4; ++r) pk[r] = f2bf(v[r]);
    *(u16x4*)(xs + (row << 6) + (((c4 >> 1) ^ (row & 7)) << 3) + ((c4 & 1) << 2)) = pk;
  }
  __syncthreads();

  if (w == 0) {  // layer 1: one wave computes hidden[16][64]
    bf16x8 a1[2];
#pragma unroll
    for (int ks = 0; ks < 2; ++ks) {
      int c = ks * 4 + q;
      a1[ks] = *(const bf16x8*)(xs + (lr << 6) + ((c ^ (lr & 7)) << 3));
    }
#pragma unroll
    for (int nf = 0; nf < 4; ++nf) {
      f32x4 h = (f32x4){0.f, 0.f, 0.f, 0.f};
#pragma unroll
      for (int ks = 0; ks < 2; ++ks) {
        int c = ks * 4 + q;
        int nr = nf * 16 + lr;
        bf16x8 b = *(const bf16x8*)(w1T + (nr << 6) + ((c ^ (nr & 7)) << 3));
        h = __builtin_amdgcn_mfma_f32_16x16x32_bf16(a1[ks], b, h, 0, 0, 0);
      }
      float bias = fb1[nf * 16 + lr];
#pragma unroll
      for (int r = 0; r < 4; ++r) {
        float v = h[r] + bias;
        v = v > 0.f ? v : 0.f;
        int row = q * 4 + r, n = nf * 16 + lr;
        h1s[(row << 6) + (((n >> 3) ^ (row & 7)) << 3) + (n & 7)] = (short)f2bf(v);
      }
    }
  }
  __syncthreads();

  // layer 2: all waves, accumulate straight into einsum acc
  bf16x8 a2[2];
#pragma unroll
  for (int ks = 0; ks < 2; ++ks) {
    int c = ks * 4 + q;
    a2[ks] = *(const bf16x8*)(h1s + (lr << 6) + ((c ^ (lr & 7)) << 3));
  }
#pragma unroll
  for (int nf = 0; nf < 2; ++nf) {
    int h = w * 32 + nf * 16 + lr;
#pragma unroll
    for (int ks = 0; ks < 2; ++ks) {
      int c = ks * 4 + q;
      bf16x8 b = *(const bf16x8*)(bT + (h << 6) + ((c ^ (h & 7)) << 3));
      acc[nf] = __builtin_amdgcn_mfma_f32_16x16x32_bf16(a2[ks], b, acc[nf], 0, 0, 0);
    }
    float bias = fb2[h];
#pragma unroll
    for (int r = 0; r < 4; ++r) {
      size_t o = ((size_t)batch * 2048 + j0 + q * 4 + r) * 128 + h;
      out[o] = acc[nf][r] + bias;
    }
  }
}

extern "C" void kernel_launch(void* const* d_in, const int* in_sizes, int n_in,
                              void* d_out, int out_size, void* d_ws, size_t ws_size,
                              hipStream_t stream) {
  const float* x    = (const float*)d_in[0];
  const float* edge = (const float*)d_in[1];
  const float* fw1  = (const float*)d_in[2];
  const float* fb1  = (const float*)d_in[3];
  const float* fw2  = (const float*)d_in[4];
  const float* fb2  = (const float*)d_in[5];
  const float* gw1  = (const float*)d_in[6];
  const float* gb1  = (const float*)d_in[7];
  const float* gw2  = (const float*)d_in[8];
  const float* gb2  = (const float*)d_in[9];
  float* out = (float*)d_out;

  unsigned short* gxF = (unsigned short*)d_ws;  // [8][32][8][2][64][8] bf16, 4 MB

  hipLaunchKernelGGL(k_gx, dim3(256), dim3(256), 0, stream, x, gw1, gb1, gw2, gb2, gxF);
  hipLaunchKernelGGL(k_main, dim3(1024), dim3(256), 0, stream, edge, gxF, x,
                     fw1, fb1, fw2, fb2, out);
}

// Round 6
// 245.799 us; speedup vs baseline: 1.0805x; 1.0805x over previous
//
#include <hip/hip_runtime.h>

// Node_GCN: out[n,j,h] = FF_f(x)[n,j,h] + sum_i edge[n,i,j] * FF_g(cat(x,x))[n,i,h]
// fp32 globals, bf16 MFMA internals (abs threshold 9.56; trunc-pack edge raises
// absmax ~2->~4-5, still well under).
// N=8, m=2048, D_IN=64, H=128.
//
//   k_gx  : gxF = sender MLP output in MFMA B-FRAGMENT ORDER
//           gxF[batch][kk][hb][ks][lane][8] -> k_main B-load = base + l*16B, coalesced.
//           v7 = v6: vectorized f32x4 weight staging (saved ~16-24 us vs scalar).
//   k_main: out[n,j,h] = edge^T @ gx + self_MLP(x_j)   fused, pure store (no RMW)
//           v7 = v5 geometry (best measured): 512 blocks (2/CU), tile 32j x 128h,
//           K=2048 in BK=64 steps. Waves split h 4-ways (dup-free gx), share both
//           j-halves. eT double-buffered, 1 LDS-only barrier/step (lgkmcnt(0)+
//           s_barrier; register prefetches stay in flight; counted vmcnt at use).
//           Edge prefetch dist 2, gx dist 1. setprio(1) around MFMA.
//           NEW: edge fp32->bf16 by TRUNCATION (1 shift vs ~4-op rounding).
//           [measured ladder: 16j/1024blk = 93us regardless of load scheme;
//            32j/512blk ~52-60us -> keep 32j.]

typedef __attribute__((ext_vector_type(8))) short bf16x8;
typedef __attribute__((ext_vector_type(4))) unsigned short u16x4;
typedef __attribute__((ext_vector_type(4))) float f32x4;

static __device__ __forceinline__ unsigned short f2bf(float f) {
  union { float f; unsigned int i; } c; c.f = f;
  return (unsigned short)((c.i + 0x7fffu + ((c.i >> 16) & 1u)) >> 16);
}
static __device__ __forceinline__ unsigned short f2bf_trunc(float f) {
  union { float f; unsigned int i; } c; c.f = f;
  return (unsigned short)(c.i >> 16);
}

// LDS-only barrier: make this wave's ds_writes visible, sync, do NOT drain vmcnt.
#define LBAR() do { \
  asm volatile("s_waitcnt lgkmcnt(0)" ::: "memory"); \
  __builtin_amdgcn_s_barrier(); \
} while (0)

// ---------------- k_gx: sender MLP, fragment-ordered bf16 store (64 rows/block, 4 waves) ----------------
__global__ __launch_bounds__(256) void k_gx(
    const float* __restrict__ x,
    const float* __restrict__ gw1,
    const float* __restrict__ gb1,
    const float* __restrict__ gw2,
    const float* __restrict__ gb2,
    unsigned short* __restrict__ gxF)
{
  __shared__ short xs[64 * 64];     // 8 KB
  __shared__ short w1T[128 * 64];   // 16 KB  folded gw1' transposed [n][k], k<64
  __shared__ short w2T[128 * 128];  // 32 KB  gw2T [n][k], k<128
  __shared__ short h2s[64 * 128];   // 16 KB

  const int t = threadIdx.x;
  const int R0 = blockIdx.x * 64;

  // vectorized weight staging: f32x4 global loads (n is the minor dim of gw1/gw2)
  for (int idx4 = t; idx4 < 64 * 32; idx4 += 256) {   // gw1: k<64, n<128
    int k = idx4 >> 5, n0 = (idx4 & 31) << 2;
    f32x4 v1 = *(const f32x4*)(gw1 + (idx4 << 2));
    f32x4 v2 = *(const f32x4*)(gw1 + 64 * 128 + (idx4 << 2));  // fold cat(x,x)
#pragma unroll
    for (int r = 0; r < 4; ++r) {
      int n = n0 + r;
      w1T[(n << 6) + (((k >> 3) ^ (n & 7)) << 3) + (k & 7)] = (short)f2bf(v1[r] + v2[r]);
    }
  }
  for (int idx4 = t; idx4 < 128 * 32; idx4 += 256) {  // gw2: k<128, n<128
    int k = idx4 >> 5, n0 = (idx4 & 31) << 2;
    f32x4 v = *(const f32x4*)(gw2 + (idx4 << 2));
#pragma unroll
    for (int r = 0; r < 4; ++r) {
      int n = n0 + r;
      w2T[(n << 7) + (((k >> 3) ^ (n & 7)) << 3) + (k & 7)] = (short)f2bf(v[r]);
    }
  }
  for (int s = t; s < 64 * 16; s += 256) {
    int row = s >> 4, c4 = s & 15;
    f32x4 v = *(const f32x4*)(x + (size_t)(R0 + row) * 64 + c4 * 4);
    u16x4 pk;
#pragma unroll
    for (int r = 0; r < 4; ++r) pk[r] = f2bf(v[r]);
    *(u16x4*)(xs + (row << 6) + (((c4 >> 1) ^ (row & 7)) << 3) + ((c4 & 1) << 2)) = pk;
  }
  __syncthreads();

  const int w = t >> 6, l = t & 63;
  const int lr = l & 15, q = l >> 4;
  const int mrow = w * 16 + lr;

  bf16x8 a[2];
#pragma unroll
  for (int ks = 0; ks < 2; ++ks) {
    int c = ks * 4 + q;
    a[ks] = *(const bf16x8*)(xs + (mrow << 6) + ((c ^ (mrow & 7)) << 3));
  }

  f32x4 acc;
#pragma unroll
  for (int nf = 0; nf < 8; ++nf) {
    acc = (f32x4){0.f, 0.f, 0.f, 0.f};
#pragma unroll
    for (int ks = 0; ks < 2; ++ks) {
      int c = ks * 4 + q;
      int nr = nf * 16 + lr;
      bf16x8 b = *(const bf16x8*)(w1T + (nr << 6) + ((c ^ (nr & 7)) << 3));
      acc = __builtin_amdgcn_mfma_f32_16x16x32_bf16(a[ks], b, acc, 0, 0, 0);
    }
    float bias = gb1[nf * 16 + lr];
#pragma unroll
    for (int r = 0; r < 4; ++r) {
      float v = acc[r] + bias;
      v = v > 0.f ? v : 0.f;
      int row = w * 16 + q * 4 + r, n = nf * 16 + lr;
      h2s[(row << 7) + (((n >> 3) ^ (row & 7)) << 3) + (n & 7)] = (short)f2bf(v);
    }
  }
  __syncthreads();

  bf16x8 a2[4];
#pragma unroll
  for (int ks = 0; ks < 4; ++ks) {
    int c = ks * 4 + q;
    a2[ks] = *(const bf16x8*)(h2s + (mrow << 7) + ((c ^ (mrow & 7)) << 3));
  }
  // fragment-ordered store: this lane holds rows i = R0 + w*16 + q*4 + 0..3, col h = nf*16+lr.
  const int batch = R0 >> 11;
  const int kk = (R0 & 2047) >> 6;
  unsigned short* gbase = gxF + (size_t)batch * (128 * 2048) + (size_t)kk * (128 * 64);
  const int cch = w * 2 + (q >> 1);
  const int ks2 = cch >> 2, qq = cch & 3, r8 = (q & 1) * 4;
#pragma unroll
  for (int nf = 0; nf < 8; ++nf) {
    acc = (f32x4){0.f, 0.f, 0.f, 0.f};
#pragma unroll
    for (int ks = 0; ks < 4; ++ks) {
      int c = ks * 4 + q;
      int nr = nf * 16 + lr;
      bf16x8 b = *(const bf16x8*)(w2T + (nr << 7) + ((c ^ (nr & 7)) << 3));
      acc = __builtin_amdgcn_mfma_f32_16x16x32_bf16(a2[ks], b, acc, 0, 0, 0);
    }
    float bias = gb2[nf * 16 + lr];
    u16x4 pk;
#pragma unroll
    for (int r = 0; r < 4; ++r) pk[r] = f2bf(acc[r] + bias);
    *(u16x4*)(gbase + (((nf * 2 + ks2) * 64 + qq * 16 + lr) << 3) + r8) = pk;
  }
}

// ---------------- k_main: fused einsum + self-MLP ----------------
__global__ __launch_bounds__(256, 2) void k_main(
    const float* __restrict__ edge,
    const unsigned short* __restrict__ gxF,
    const float* __restrict__ x,
    const float* __restrict__ fw1,
    const float* __restrict__ fb1,
    const float* __restrict__ fw2,
    const float* __restrict__ fb2,
    float* __restrict__ out)
{
  // eT[buf][jj 0..31][ii 0..63]: stride 72 shorts, chunk swizzle (ii>>3)^(jj>>3).
  // gx B-fragments read straight from global in fragment order (coalesced 16B/lane).
  __shared__ short eT[2][32 * 72]; // 9 KB double-buffered edge^T tile
  __shared__ short bT[128 * 64];   // 16 KB (epilogue: fw2T)
  __shared__ short xs[32 * 64];    // 4 KB  (epilogue)
  __shared__ short w1T[64 * 64];   // 8 KB  (epilogue)
  __shared__ short h1s[32 * 64];   // 4 KB  (epilogue)   total ~41 KB

  const int t = threadIdx.x;
  const int batch = blockIdx.x & 7;   // XCD-pinned: each XCD sees one batch's gx (512 KB)
  const int j0 = (blockIdx.x >> 3) * 32;

  const int w = t >> 6, l = t & 63;   // wave w owns h-range [w*32, w*32+32), both j-halves
  const int lr = l & 15, q = l >> 4;

  // edge loader roles: 256 threads cover 64i x 32j fp32 tile, f32x8 each
  const int e_ii = t >> 2;          // 0..63
  const int e_cj = t & 3;           // 0..3  (8 j each)

  const float* ep = edge + (size_t)batch * 2048 * 2048 + (size_t)e_ii * 2048 + j0 + e_cj * 8;
  // fragment-order gx base: + w*2048 selects this wave's h-blocks, + l*8 the lane slot
  const unsigned short* gp = gxF + (size_t)batch * (128 * 2048) + w * 2048 + (size_t)l * 8;

  f32x4 acc[4];  // [jm][nf] flattened
#pragma unroll
  for (int i = 0; i < 4; ++i) acc[i] = (f32x4){0.f, 0.f, 0.f, 0.f};

  // ---- helpers (all indices static after unroll) ----
  auto lde = [&](int kk, f32x4 er[2]) {
    const float* p = ep + (size_t)kk * 64 * 2048;
    er[0] = *(const f32x4*)p;
    er[1] = *(const f32x4*)(p + 4);
  };
  auto ldg = [&](int kk, bf16x8 gf[4]) {  // 4 coalesced 16B/lane loads (1 KB/wave each)
    const unsigned short* p = gp + kk * 8192;
#pragma unroll
    for (int nf = 0; nf < 2; ++nf)
#pragma unroll
      for (int ks = 0; ks < 2; ++ks)
        gf[nf * 2 + ks] = *(const bf16x8*)(p + nf * 1024 + ks * 512);
  };
  auto st_e = [&](int buf, const f32x4 er[2]) {
#pragma unroll
    for (int u = 0; u < 8; ++u) {
      int jj = e_cj * 8 + u;
      float v = (u < 4) ? er[0][u & 3] : er[1][u & 3];
      // truncation (round-toward-zero): 1 VALU op vs ~4 for RNE; error budget ok
      eT[buf][jj * 72 + (((e_ii >> 3) ^ e_cj) << 3) + (e_ii & 7)] = (short)f2bf_trunc(v);
    }
  };
  auto comp = [&](int buf, const bf16x8 gf[4]) {
    __builtin_amdgcn_s_setprio(1);
#pragma unroll
    for (int ks = 0; ks < 2; ++ks) {
      const int c = ks * 4 + q;
      bf16x8 a[2];
#pragma unroll
      for (int jm = 0; jm < 2; ++jm) {
        int jj = jm * 16 + lr;
        a[jm] = *(const bf16x8*)(&eT[buf][jj * 72 + ((c ^ (jj >> 3)) << 3)]);
      }
#pragma unroll
      for (int jm = 0; jm < 2; ++jm)
#pragma unroll
        for (int nf = 0; nf < 2; ++nf)
          acc[jm * 2 + nf] = __builtin_amdgcn_mfma_f32_16x16x32_bf16(a[jm], gf[nf * 2 + ks],
                                                                    acc[jm * 2 + nf], 0, 0, 0);
    }
    __builtin_amdgcn_s_setprio(0);
  };

  // ---- main K loop: 32 tiles, 2x unrolled, eT double-buffered, 1 LDS-barrier/step ----
  f32x4 erA[2], erB[2];
  bf16x8 gfA[4], gfB[4];

  lde(0, erA);
  ldg(0, gfA);
  lde(1, erB);
  st_e(0, erA);
  LBAR();              // gfA, erB stay in flight

#pragma unroll 1
  for (int mm = 0; mm < 15; ++mm) {
    // step 2mm: read eT0 + gfA
    ldg(2 * mm + 1, gfB);
    lde(2 * mm + 2, erA);
    comp(0, gfA);      // counted vmcnt for gfA, not 0
    st_e(1, erB);      // eT for step 2mm+1 (erB loaded a full step ago)
    LBAR();
    // step 2mm+1: read eT1 + gfB
    ldg(2 * mm + 2, gfA);
    lde(2 * mm + 3, erB);
    comp(1, gfB);
    st_e(0, erA);      // eT for step 2mm+2
    LBAR();
  }
  // tail: steps 30, 31
  ldg(31, gfB);
  comp(0, gfA);        // step 30
  st_e(1, erB);
  LBAR();
  comp(1, gfB);        // step 31

  // ---- fused self-MLP epilogue: acc += relu(x_j @ fw1 + b1) @ fw2 + b2 ----
  for (int idx = t; idx < 64 * 64; idx += 256) {
    int k = idx >> 6, n = idx & 63;  // fw1[k][n]
    w1T[(n << 6) + (((k >> 3) ^ (n & 7)) << 3) + (k & 7)] = (short)f2bf(fw1[idx]);
  }
  for (int idx = t; idx < 64 * 128; idx += 256) {
    int k = idx >> 7, n = idx & 127;  // fw2[k][n] -> bT as fw2T
    bT[(n << 6) + (((k >> 3) ^ (n & 7)) << 3) + (k & 7)] = (short)f2bf(fw2[idx]);
  }
  for (int s = t; s < 32 * 16; s += 256) {
    int row = s >> 4, c4 = s & 15;
    f32x4 v = *(const f32x4*)(x + (size_t)(batch * 2048 + j0 + row) * 64 + c4 * 4);
    u16x4 pk;
#pragma unroll
    for (int r = 0; r < 4; ++r) pk[r] = f2bf(v[r]);
    *(u16x4*)(xs + (row << 6) + (((c4 >> 1) ^ (row & 7)) << 3) + ((c4 & 1) << 2)) = pk;
  }
  __syncthreads();

  if (w < 2) {  // layer 1: waves 0,1 compute hidden[32][64]
    const int mrow = w * 16 + lr;
    bf16x8 a1[2];
#pragma unroll
    for (int ks = 0; ks < 2; ++ks) {
      int c = ks * 4 + q;
      a1[ks] = *(const bf16x8*)(xs + (mrow << 6) + ((c ^ (mrow & 7)) << 3));
    }
#pragma unroll
    for (int nf = 0; nf < 4; ++nf) {
      f32x4 h = (f32x4){0.f, 0.f, 0.f, 0.f};
#pragma unroll
      for (int ks = 0; ks < 2; ++ks) {
        int c = ks * 4 + q;
        int nr = nf * 16 + lr;
        bf16x8 b = *(const bf16x8*)(w1T + (nr << 6) + ((c ^ (nr & 7)) << 3));
        h = __builtin_amdgcn_mfma_f32_16x16x32_bf16(a1[ks], b, h, 0, 0, 0);
      }
      float bias = fb1[nf * 16 + lr];
#pragma unroll
      for (int r = 0; r < 4; ++r) {
        float v = h[r] + bias;
        v = v > 0.f ? v : 0.f;
        int row = w * 16 + q * 4 + r, n = nf * 16 + lr;
        h1s[(row << 6) + (((n >> 3) ^ (row & 7)) << 3) + (n & 7)] = (short)f2bf(v);
      }
    }
  }
  __syncthreads();

  // layer 2: all waves, accumulate straight into einsum acc
  bf16x8 a2[2][2];  // [jm][ks]
#pragma unroll
  for (int jm = 0; jm < 2; ++jm)
#pragma unroll
    for (int ks = 0; ks < 2; ++ks) {
      int c = ks * 4 + q;
      int mrow = jm * 16 + lr;
      a2[jm][ks] = *(const bf16x8*)(h1s + (mrow << 6) + ((c ^ (mrow & 7)) << 3));
    }
#pragma unroll
  for (int jm = 0; jm < 2; ++jm)
#pragma unroll
    for (int nf = 0; nf < 2; ++nf) {
      int h = w * 32 + nf * 16 + lr;
#pragma unroll
      for (int ks = 0; ks < 2; ++ks) {
        int c = ks * 4 + q;
        bf16x8 b = *(const bf16x8*)(bT + (h << 6) + ((c ^ (h & 7)) << 3));
        acc[jm * 2 + nf] = __builtin_amdgcn_mfma_f32_16x16x32_bf16(a2[jm][ks], b,
                                                                  acc[jm * 2 + nf], 0, 0, 0);
      }
      float bias = fb2[h];
#pragma unroll
      for (int r = 0; r < 4; ++r) {
        size_t o = ((size_t)batch * 2048 + j0 + jm * 16 + q * 4 + r) * 128 + h;
        out[o] = acc[jm * 2 + nf][r] + bias;
      }
    }
}

extern "C" void kernel_launch(void* const* d_in, const int* in_sizes, int n_in,
                              void* d_out, int out_size, void* d_ws, size_t ws_size,
                              hipStream_t stream) {
  const float* x    = (const float*)d_in[0];
  const float* edge = (const float*)d_in[1];
  const float* fw1  = (const float*)d_in[2];
  const float* fb1  = (const float*)d_in[3];
  const float* fw2  = (const float*)d_in[4];
  const float* fb2  = (const float*)d_in[5];
  const float* gw1  = (const float*)d_in[6];
  const float* gb1  = (const float*)d_in[7];
  const float* gw2  = (const float*)d_in[8];
  const float* gb2  = (const float*)d_in[9];
  float* out = (float*)d_out;

  unsigned short* gxF = (unsigned short*)d_ws;  // [8][32][8][2][64][8] bf16, 4 MB

  hipLaunchKernelGGL(k_gx, dim3(256), dim3(256), 0, stream, x, gw1, gb1, gw2, gb2, gxF);
  hipLaunchKernelGGL(k_main, dim3(512), dim3(256), 0, stream, edge, gxF, x,
                     fw1, fb1, fw2, fb2, out);
}

// Round 7
// 244.669 us; speedup vs baseline: 1.0855x; 1.0046x over previous
//
#include <hip/hip_runtime.h>

// Node_GCN: out[n,j,h] = FF_f(x)[n,j,h] + sum_i edge[n,i,j] * FF_g(cat(x,x))[n,i,h]
// fp32 globals, bf16 MFMA internals (abs threshold 9.56; measured absmax 2.0).
// N=8, m=2048, D_IN=64, H=128.
//
//   k_gx  : gxF = sender MLP output in MFMA B-FRAGMENT ORDER
//           gxF[batch][kk][hb][ks][lane][8] -> k_main B-load = base + l*16B, coalesced.
//   k_main: out[n,j,h] = edge^T @ gx + self_MLP(x_j)   fused, pure store (no RMW)
//           v8: 512 blocks (2/CU), tile 32j x 128h, K=2048 in BK=64 steps.
//           NEW: edge prefetch DISTANCE 4 (erA..erD, static mod-4 schedule).
//           Little's law: 24.6 GB/s/CU @ ~900cy needs ~22KB in flight/CU; dist-2
//           issued bursts ~1 step before use (v5/v7, latency-exposed). dist-4 =
//           64KB/CU in flight, load->use gap ~3 steps (~5000cy cover).
//           eT double-buffered, 1 LDS-only barrier/step (LBAR: lgkmcnt(0)+s_barrier,
//           register prefetches cross barriers; counted vmcnt at use). setprio(1)
//           around MFMA. Edge pack by truncation.
//           [ladder: 16j/1024blk = 93-108us (twice) -> keep 32j/512blk;
//            occupancy theory dead; in-flight-bytes theory under test here.]

typedef __attribute__((ext_vector_type(8))) short bf16x8;
typedef __attribute__((ext_vector_type(4))) unsigned short u16x4;
typedef __attribute__((ext_vector_type(4))) float f32x4;

static __device__ __forceinline__ unsigned short f2bf(float f) {
  union { float f; unsigned int i; } c; c.f = f;
  return (unsigned short)((c.i + 0x7fffu + ((c.i >> 16) & 1u)) >> 16);
}
static __device__ __forceinline__ unsigned short f2bf_trunc(float f) {
  union { float f; unsigned int i; } c; c.f = f;
  return (unsigned short)(c.i >> 16);
}

// LDS-only barrier: make this wave's ds_writes visible, sync, do NOT drain vmcnt.
#define LBAR() do { \
  asm volatile("s_waitcnt lgkmcnt(0)" ::: "memory"); \
  __builtin_amdgcn_s_barrier(); \
} while (0)

// ---------------- k_gx: sender MLP, fragment-ordered bf16 store (64 rows/block, 4 waves) ----------------
__global__ __launch_bounds__(256) void k_gx(
    const float* __restrict__ x,
    const float* __restrict__ gw1,
    const float* __restrict__ gb1,
    const float* __restrict__ gw2,
    const float* __restrict__ gb2,
    unsigned short* __restrict__ gxF)
{
  __shared__ short xs[64 * 64];     // 8 KB
  __shared__ short w1T[128 * 64];   // 16 KB  folded gw1' transposed [n][k], k<64
  __shared__ short w2T[128 * 128];  // 32 KB  gw2T [n][k], k<128
  __shared__ short h2s[64 * 128];   // 16 KB

  const int t = threadIdx.x;
  const int R0 = blockIdx.x * 64;

  // vectorized weight staging: f32x4 global loads (n is the minor dim of gw1/gw2)
  for (int idx4 = t; idx4 < 64 * 32; idx4 += 256) {   // gw1: k<64, n<128
    int k = idx4 >> 5, n0 = (idx4 & 31) << 2;
    f32x4 v1 = *(const f32x4*)(gw1 + (idx4 << 2));
    f32x4 v2 = *(const f32x4*)(gw1 + 64 * 128 + (idx4 << 2));  // fold cat(x,x)
#pragma unroll
    for (int r = 0; r < 4; ++r) {
      int n = n0 + r;
      w1T[(n << 6) + (((k >> 3) ^ (n & 7)) << 3) + (k & 7)] = (short)f2bf(v1[r] + v2[r]);
    }
  }
  for (int idx4 = t; idx4 < 128 * 32; idx4 += 256) {  // gw2: k<128, n<128
    int k = idx4 >> 5, n0 = (idx4 & 31) << 2;
    f32x4 v = *(const f32x4*)(gw2 + (idx4 << 2));
#pragma unroll
    for (int r = 0; r < 4; ++r) {
      int n = n0 + r;
      w2T[(n << 7) + (((k >> 3) ^ (n & 7)) << 3) + (k & 7)] = (short)f2bf(v[r]);
    }
  }
  for (int s = t; s < 64 * 16; s += 256) {
    int row = s >> 4, c4 = s & 15;
    f32x4 v = *(const f32x4*)(x + (size_t)(R0 + row) * 64 + c4 * 4);
    u16x4 pk;
#pragma unroll
    for (int r = 0; r < 4; ++r) pk[r] = f2bf(v[r]);
    *(u16x4*)(xs + (row << 6) + (((c4 >> 1) ^ (row & 7)) << 3) + ((c4 & 1) << 2)) = pk;
  }
  __syncthreads();

  const int w = t >> 6, l = t & 63;
  const int lr = l & 15, q = l >> 4;
  const int mrow = w * 16 + lr;

  bf16x8 a[2];
#pragma unroll
  for (int ks = 0; ks < 2; ++ks) {
    int c = ks * 4 + q;
    a[ks] = *(const bf16x8*)(xs + (mrow << 6) + ((c ^ (mrow & 7)) << 3));
  }

  f32x4 acc;
#pragma unroll
  for (int nf = 0; nf < 8; ++nf) {
    acc = (f32x4){0.f, 0.f, 0.f, 0.f};
#pragma unroll
    for (int ks = 0; ks < 2; ++ks) {
      int c = ks * 4 + q;
      int nr = nf * 16 + lr;
      bf16x8 b = *(const bf16x8*)(w1T + (nr << 6) + ((c ^ (nr & 7)) << 3));
      acc = __builtin_amdgcn_mfma_f32_16x16x32_bf16(a[ks], b, acc, 0, 0, 0);
    }
    float bias = gb1[nf * 16 + lr];
#pragma unroll
    for (int r = 0; r < 4; ++r) {
      float v = acc[r] + bias;
      v = v > 0.f ? v : 0.f;
      int row = w * 16 + q * 4 + r, n = nf * 16 + lr;
      h2s[(row << 7) + (((n >> 3) ^ (row & 7)) << 3) + (n & 7)] = (short)f2bf(v);
    }
  }
  __syncthreads();

  bf16x8 a2[4];
#pragma unroll
  for (int ks = 0; ks < 4; ++ks) {
    int c = ks * 4 + q;
    a2[ks] = *(const bf16x8*)(h2s + (mrow << 7) + ((c ^ (mrow & 7)) << 3));
  }
  // fragment-ordered store: this lane holds rows i = R0 + w*16 + q*4 + 0..3, col h = nf*16+lr.
  const int batch = R0 >> 11;
  const int kk = (R0 & 2047) >> 6;
  unsigned short* gbase = gxF + (size_t)batch * (128 * 2048) + (size_t)kk * (128 * 64);
  const int cch = w * 2 + (q >> 1);
  const int ks2 = cch >> 2, qq = cch & 3, r8 = (q & 1) * 4;
#pragma unroll
  for (int nf = 0; nf < 8; ++nf) {
    acc = (f32x4){0.f, 0.f, 0.f, 0.f};
#pragma unroll
    for (int ks = 0; ks < 4; ++ks) {
      int c = ks * 4 + q;
      int nr = nf * 16 + lr;
      bf16x8 b = *(const bf16x8*)(w2T + (nr << 7) + ((c ^ (nr & 7)) << 3));
      acc = __builtin_amdgcn_mfma_f32_16x16x32_bf16(a2[ks], b, acc, 0, 0, 0);
    }
    float bias = gb2[nf * 16 + lr];
    u16x4 pk;
#pragma unroll
    for (int r = 0; r < 4; ++r) pk[r] = f2bf(acc[r] + bias);
    *(u16x4*)(gbase + (((nf * 2 + ks2) * 64 + qq * 16 + lr) << 3) + r8) = pk;
  }
}

// ---------------- k_main: fused einsum + self-MLP ----------------
__global__ __launch_bounds__(256, 2) void k_main(
    const float* __restrict__ edge,
    const unsigned short* __restrict__ gxF,
    const float* __restrict__ x,
    const float* __restrict__ fw1,
    const float* __restrict__ fb1,
    const float* __restrict__ fw2,
    const float* __restrict__ fb2,
    float* __restrict__ out)
{
  // eT[buf][jj 0..31][ii 0..63]: stride 72 shorts, chunk swizzle (ii>>3)^(jj>>3).
  // gx B-fragments read straight from global in fragment order (coalesced 16B/lane).
  __shared__ short eT[2][32 * 72]; // 9 KB double-buffered edge^T tile
  __shared__ short bT[128 * 64];   // 16 KB (epilogue: fw2T)
  __shared__ short xs[32 * 64];    // 4 KB  (epilogue)
  __shared__ short w1T[64 * 64];   // 8 KB  (epilogue)
  __shared__ short h1s[32 * 64];   // 4 KB  (epilogue)   total ~41 KB

  const int t = threadIdx.x;
  const int batch = blockIdx.x & 7;   // XCD-pinned: each XCD sees one batch's gx (512 KB)
  const int j0 = (blockIdx.x >> 3) * 32;

  const int w = t >> 6, l = t & 63;   // wave w owns h-range [w*32, w*32+32), both j-halves
  const int lr = l & 15, q = l >> 4;

  // edge loader roles: 256 threads cover 64i x 32j fp32 tile, f32x8 each
  const int e_ii = t >> 2;          // 0..63
  const int e_cj = t & 3;           // 0..3  (8 j each)

  const float* ep = edge + (size_t)batch * 2048 * 2048 + (size_t)e_ii * 2048 + j0 + e_cj * 8;
  // fragment-order gx base: + w*2048 selects this wave's h-blocks, + l*8 the lane slot
  const unsigned short* gp = gxF + (size_t)batch * (128 * 2048) + w * 2048 + (size_t)l * 8;

  f32x4 acc[4];  // [jm][nf] flattened
#pragma unroll
  for (int i = 0; i < 4; ++i) acc[i] = (f32x4){0.f, 0.f, 0.f, 0.f};

  // ---- helpers (all indices static after unroll) ----
  auto lde = [&](int kk, f32x4 er[2]) {
    const float* p = ep + (size_t)kk * 64 * 2048;
    er[0] = *(const f32x4*)p;
    er[1] = *(const f32x4*)(p + 4);
  };
  auto ldg = [&](int kk, bf16x8 gf[4]) {  // 4 coalesced 16B/lane loads (1 KB/wave each)
    const unsigned short* p = gp + kk * 8192;
#pragma unroll
    for (int nf = 0; nf < 2; ++nf)
#pragma unroll
      for (int ks = 0; ks < 2; ++ks)
        gf[nf * 2 + ks] = *(const bf16x8*)(p + nf * 1024 + ks * 512);
  };
  auto st_e = [&](int buf, const f32x4 er[2]) {
#pragma unroll
    for (int u = 0; u < 8; ++u) {
      int jj = e_cj * 8 + u;
      float v = (u < 4) ? er[0][u & 3] : er[1][u & 3];
      eT[buf][jj * 72 + (((e_ii >> 3) ^ e_cj) << 3) + (e_ii & 7)] = (short)f2bf_trunc(v);
    }
  };
  auto comp = [&](int buf, const bf16x8 gf[4]) {
    __builtin_amdgcn_s_setprio(1);
#pragma unroll
    for (int ks = 0; ks < 2; ++ks) {
      const int c = ks * 4 + q;
      bf16x8 a[2];
#pragma unroll
      for (int jm = 0; jm < 2; ++jm) {
        int jj = jm * 16 + lr;
        a[jm] = *(const bf16x8*)(&eT[buf][jj * 72 + ((c ^ (jj >> 3)) << 3)]);
      }
#pragma unroll
      for (int jm = 0; jm < 2; ++jm)
#pragma unroll
        for (int nf = 0; nf < 2; ++nf)
          acc[jm * 2 + nf] = __builtin_amdgcn_mfma_f32_16x16x32_bf16(a[jm], gf[nf * 2 + ks],
                                                                    acc[jm * 2 + nf], 0, 0, 0);
    }
    __builtin_amdgcn_s_setprio(0);
  };

  // ---- main K loop: 32 steps, distance-4 edge prefetch (erA..D), distance-1 gx ----
  // step s: ldg(s+1 -> gf[(s+1)&1]); lde(s+4 -> er[s&3]); comp(eT[s&1], gf[s&1]);
  //         st_e(eT[(s+1)&1], er[(s+1)&3]); LBAR
  // er[t&3] holds tile t from its lde at step t-4 until its st_e at step t-1.
  f32x4 erA[2], erB[2], erC[2], erD[2];
  bf16x8 gfA[4], gfB[4];

  lde(0, erA); lde(1, erB); lde(2, erC); lde(3, erD);
  ldg(0, gfA);
  st_e(0, erA);
  LBAR();              // gfA, erB..erD stay in flight across the barrier

#pragma unroll 1
  for (int mm = 0; mm < 7; ++mm) {
    const int s = mm * 4;
    ldg(s + 1, gfB); lde(s + 4, erA); comp(0, gfA); st_e(1, erB); LBAR();
    ldg(s + 2, gfA); lde(s + 5, erB); comp(1, gfB); st_e(0, erC); LBAR();
    ldg(s + 3, gfB); lde(s + 6, erC); comp(0, gfA); st_e(1, erD); LBAR();
    ldg(s + 4, gfA); lde(s + 7, erD); comp(1, gfB); st_e(0, erA); LBAR();
  }
  // steps 28..31 (no more lde; tiles 28..31 already in erA..erD)
  ldg(29, gfB); comp(0, gfA); st_e(1, erB); LBAR();
  ldg(30, gfA); comp(1, gfB); st_e(0, erC); LBAR();
  ldg(31, gfB); comp(0, gfA); st_e(1, erD); LBAR();
  comp(1, gfB);

  // ---- fused self-MLP epilogue: acc += relu(x_j @ fw1 + b1) @ fw2 + b2 ----
  for (int idx = t; idx < 64 * 64; idx += 256) {
    int k = idx >> 6, n = idx & 63;  // fw1[k][n]
    w1T[(n << 6) + (((k >> 3) ^ (n & 7)) << 3) + (k & 7)] = (short)f2bf(fw1[idx]);
  }
  for (int idx = t; idx < 64 * 128; idx += 256) {
    int k = idx >> 7, n = idx & 127;  // fw2[k][n] -> bT as fw2T
    bT[(n << 6) + (((k >> 3) ^ (n & 7)) << 3) + (k & 7)] = (short)f2bf(fw2[idx]);
  }
  for (int s = t; s < 32 * 16; s += 256) {
    int row = s >> 4, c4 = s & 15;
    f32x4 v = *(const f32x4*)(x + (size_t)(batch * 2048 + j0 + row) * 64 + c4 * 4);
    u16x4 pk;
#pragma unroll
    for (int r = 0; r < 4; ++r) pk[r] = f2bf(v[r]);
    *(u16x4*)(xs + (row << 6) + (((c4 >> 1) ^ (row & 7)) << 3) + ((c4 & 1) << 2)) = pk;
  }
  __syncthreads();

  if (w < 2) {  // layer 1: waves 0,1 compute hidden[32][64]
    const int mrow = w * 16 + lr;
    bf16x8 a1[2];
#pragma unroll
    for (int ks = 0; ks < 2; ++ks) {
      int c = ks * 4 + q;
      a1[ks] = *(const bf16x8*)(xs + (mrow << 6) + ((c ^ (mrow & 7)) << 3));
    }
#pragma unroll
    for (int nf = 0; nf < 4; ++nf) {
      f32x4 h = (f32x4){0.f, 0.f, 0.f, 0.f};
#pragma unroll
      for (int ks = 0; ks < 2; ++ks) {
        int c = ks * 4 + q;
        int nr = nf * 16 + lr;
        bf16x8 b = *(const bf16x8*)(w1T + (nr << 6) + ((c ^ (nr & 7)) << 3));
        h = __builtin_amdgcn_mfma_f32_16x16x32_bf16(a1[ks], b, h, 0, 0, 0);
      }
      float bias = fb1[nf * 16 + lr];
#pragma unroll
      for (int r = 0; r < 4; ++r) {
        float v = h[r] + bias;
        v = v > 0.f ? v : 0.f;
        int row = w * 16 + q * 4 + r, n = nf * 16 + lr;
        h1s[(row << 6) + (((n >> 3) ^ (row & 7)) << 3) + (n & 7)] = (short)f2bf(v);
      }
    }
  }
  __syncthreads();

  // layer 2: all waves, accumulate straight into einsum acc
  bf16x8 a2[2][2];  // [jm][ks]
#pragma unroll
  for (int jm = 0; jm < 2; ++jm)
#pragma unroll
    for (int ks = 0; ks < 2; ++ks) {
      int c = ks * 4 + q;
      int mrow = jm * 16 + lr;
      a2[jm][ks] = *(const bf16x8*)(h1s + (mrow << 6) + ((c ^ (mrow & 7)) << 3));
    }
#pragma unroll
  for (int jm = 0; jm < 2; ++jm)
#pragma unroll
    for (int nf = 0; nf < 2; ++nf) {
      int h = w * 32 + nf * 16 + lr;
#pragma unroll
      for (int ks = 0; ks < 2; ++ks) {
        int c = ks * 4 + q;
        bf16x8 b = *(const bf16x8*)(bT + (h << 6) + ((c ^ (h & 7)) << 3));
        acc[jm * 2 + nf] = __builtin_amdgcn_mfma_f32_16x16x32_bf16(a2[jm][ks], b,
                                                                  acc[jm * 2 + nf], 0, 0, 0);
      }
      float bias = fb2[h];
#pragma unroll
      for (int r = 0; r < 4; ++r) {
        size_t o = ((size_t)batch * 2048 + j0 + jm * 16 + q * 4 + r) * 128 + h;
        out[o] = acc[jm * 2 + nf][r] + bias;
      }
    }
}

extern "C" void kernel_launch(void* const* d_in, const int* in_sizes, int n_in,
                              void* d_out, int out_size, void* d_ws, size_t ws_size,
                              hipStream_t stream) {
  const float* x    = (const float*)d_in[0];
  const float* edge = (const float*)d_in[1];
  const float* fw1  = (const float*)d_in[2];
  const float* fb1  = (const float*)d_in[3];
  const float* fw2  = (const float*)d_in[4];
  const float* fb2  = (const float*)d_in[5];
  const float* gw1  = (const float*)d_in[6];
  const float* gb1  = (const float*)d_in[7];
  const float* gw2  = (const float*)d_in[8];
  const float* gb2  = (const float*)d_in[9];
  float* out = (float*)d_out;

  unsigned short* gxF = (unsigned short*)d_ws;  // [8][32][8][2][64][8] bf16, 4 MB

  hipLaunchKernelGGL(k_gx, dim3(256), dim3(256), 0, stream, x, gw1, gb1, gw2, gb2, gxF);
  hipLaunchKernelGGL(k_main, dim3(512), dim3(256), 0, stream, edge, gxF, x,
                     fw1, fb1, fw2, fb2, out);
}

// Round 8
// 242.744 us; speedup vs baseline: 1.0941x; 1.0079x over previous
//
#include <hip/hip_runtime.h>

// Node_GCN: out[n,j,h] = FF_f(x)[n,j,h] + sum_i edge[n,i,j] * FF_g(cat(x,x))[n,i,h]
// fp32 globals, bf16 MFMA internals (abs threshold 9.56; measured absmax 2.0).
// N=8, m=2048, D_IN=64, H=128.
//
//   k_gx  : gxF = sender MLP output in MFMA B-FRAGMENT ORDER
//           gxF[batch][kk][hb][ks][lane][8] -> k_main B-load = base + l*16B, coalesced.
//   k_main: out[n,j,h] = edge^T @ gx + self_MLP(x_j)   fused, pure store (no RMW)
//           v9: 512 blocks (2/CU), tile 32j x 128h, K=2048 in BK=64 steps.
//           FIX vs v5-v8: LBAR's asm had a "memory" clobber -> backend inserted an
//           implicit vmcnt(0) drain before it (opaque asm may read any memory), so
//           every "relaxed" barrier was semantically __syncthreads and all prefetch
//           (dist-2, dist-4) was dead weight -- explaining v4==v5==v7==v8 (~245us).
//           v9 LBAR = sched_barrier(0); s_waitcnt lgkmcnt(0) [NO clobber];
//           s_barrier; sched_barrier(0)  -- the m201/m218-verified pattern:
//           ds ordering pinned at compile time, register prefetches stay in
//           flight, counted vmcnt(8) at first MFMA use of gx.
//           Edge prefetch distance 4 (erA..erD), gx distance 1. setprio around MFMA.

typedef __attribute__((ext_vector_type(8))) short bf16x8;
typedef __attribute__((ext_vector_type(4))) unsigned short u16x4;
typedef __attribute__((ext_vector_type(4))) float f32x4;

static __device__ __forceinline__ unsigned short f2bf(float f) {
  union { float f; unsigned int i; } c; c.f = f;
  return (unsigned short)((c.i + 0x7fffu + ((c.i >> 16) & 1u)) >> 16);
}
static __device__ __forceinline__ unsigned short f2bf_trunc(float f) {
  union { float f; unsigned int i; } c; c.f = f;
  return (unsigned short)(c.i >> 16);
}

// LDS-only barrier, counted-vmcnt-preserving (m201/m218 pattern):
// NO "memory" clobber (that forces an implicit vmcnt(0) drain); ordering of the
// surrounding ds ops is pinned by sched_barrier(0) instead (rule #18).
#define LBAR() do { \
  __builtin_amdgcn_sched_barrier(0); \
  asm volatile("s_waitcnt lgkmcnt(0)"); \
  __builtin_amdgcn_s_barrier(); \
  __builtin_amdgcn_sched_barrier(0); \
} while (0)

// ---------------- k_gx: sender MLP, fragment-ordered bf16 store (64 rows/block, 4 waves) ----------------
__global__ __launch_bounds__(256) void k_gx(
    const float* __restrict__ x,
    const float* __restrict__ gw1,
    const float* __restrict__ gb1,
    const float* __restrict__ gw2,
    const float* __restrict__ gb2,
    unsigned short* __restrict__ gxF)
{
  __shared__ short xs[64 * 64];     // 8 KB
  __shared__ short w1T[128 * 64];   // 16 KB  folded gw1' transposed [n][k], k<64
  __shared__ short w2T[128 * 128];  // 32 KB  gw2T [n][k], k<128
  __shared__ short h2s[64 * 128];   // 16 KB

  const int t = threadIdx.x;
  const int R0 = blockIdx.x * 64;

  // vectorized weight staging: f32x4 global loads (n is the minor dim of gw1/gw2)
  for (int idx4 = t; idx4 < 64 * 32; idx4 += 256) {   // gw1: k<64, n<128
    int k = idx4 >> 5, n0 = (idx4 & 31) << 2;
    f32x4 v1 = *(const f32x4*)(gw1 + (idx4 << 2));
    f32x4 v2 = *(const f32x4*)(gw1 + 64 * 128 + (idx4 << 2));  // fold cat(x,x)
#pragma unroll
    for (int r = 0; r < 4; ++r) {
      int n = n0 + r;
      w1T[(n << 6) + (((k >> 3) ^ (n & 7)) << 3) + (k & 7)] = (short)f2bf(v1[r] + v2[r]);
    }
  }
  for (int idx4 = t; idx4 < 128 * 32; idx4 += 256) {  // gw2: k<128, n<128
    int k = idx4 >> 5, n0 = (idx4 & 31) << 2;
    f32x4 v = *(const f32x4*)(gw2 + (idx4 << 2));
#pragma unroll
    for (int r = 0; r < 4; ++r) {
      int n = n0 + r;
      w2T[(n << 7) + (((k >> 3) ^ (n & 7)) << 3) + (k & 7)] = (short)f2bf(v[r]);
    }
  }
  for (int s = t; s < 64 * 16; s += 256) {
    int row = s >> 4, c4 = s & 15;
    f32x4 v = *(const f32x4*)(x + (size_t)(R0 + row) * 64 + c4 * 4);
    u16x4 pk;
#pragma unroll
    for (int r = 0; r < 4; ++r) pk[r] = f2bf(v[r]);
    *(u16x4*)(xs + (row << 6) + (((c4 >> 1) ^ (row & 7)) << 3) + ((c4 & 1) << 2)) = pk;
  }
  __syncthreads();

  const int w = t >> 6, l = t & 63;
  const int lr = l & 15, q = l >> 4;
  const int mrow = w * 16 + lr;

  bf16x8 a[2];
#pragma unroll
  for (int ks = 0; ks < 2; ++ks) {
    int c = ks * 4 + q;
    a[ks] = *(const bf16x8*)(xs + (mrow << 6) + ((c ^ (mrow & 7)) << 3));
  }

  f32x4 acc;
#pragma unroll
  for (int nf = 0; nf < 8; ++nf) {
    acc = (f32x4){0.f, 0.f, 0.f, 0.f};
#pragma unroll
    for (int ks = 0; ks < 2; ++ks) {
      int c = ks * 4 + q;
      int nr = nf * 16 + lr;
      bf16x8 b = *(const bf16x8*)(w1T + (nr << 6) + ((c ^ (nr & 7)) << 3));
      acc = __builtin_amdgcn_mfma_f32_16x16x32_bf16(a[ks], b, acc, 0, 0, 0);
    }
    float bias = gb1[nf * 16 + lr];
#pragma unroll
    for (int r = 0; r < 4; ++r) {
      float v = acc[r] + bias;
      v = v > 0.f ? v : 0.f;
      int row = w * 16 + q * 4 + r, n = nf * 16 + lr;
      h2s[(row << 7) + (((n >> 3) ^ (row & 7)) << 3) + (n & 7)] = (short)f2bf(v);
    }
  }
  __syncthreads();

  bf16x8 a2[4];
#pragma unroll
  for (int ks = 0; ks < 4; ++ks) {
    int c = ks * 4 + q;
    a2[ks] = *(const bf16x8*)(h2s + (mrow << 7) + ((c ^ (mrow & 7)) << 3));
  }
  // fragment-ordered store: this lane holds rows i = R0 + w*16 + q*4 + 0..3, col h = nf*16+lr.
  const int batch = R0 >> 11;
  const int kk = (R0 & 2047) >> 6;
  unsigned short* gbase = gxF + (size_t)batch * (128 * 2048) + (size_t)kk * (128 * 64);
  const int cch = w * 2 + (q >> 1);
  const int ks2 = cch >> 2, qq = cch & 3, r8 = (q & 1) * 4;
#pragma unroll
  for (int nf = 0; nf < 8; ++nf) {
    acc = (f32x4){0.f, 0.f, 0.f, 0.f};
#pragma unroll
    for (int ks = 0; ks < 4; ++ks) {
      int c = ks * 4 + q;
      int nr = nf * 16 + lr;
      bf16x8 b = *(const bf16x8*)(w2T + (nr << 7) + ((c ^ (nr & 7)) << 3));
      acc = __builtin_amdgcn_mfma_f32_16x16x32_bf16(a2[ks], b, acc, 0, 0, 0);
    }
    float bias = gb2[nf * 16 + lr];
    u16x4 pk;
#pragma unroll
    for (int r = 0; r < 4; ++r) pk[r] = f2bf(acc[r] + bias);
    *(u16x4*)(gbase + (((nf * 2 + ks2) * 64 + qq * 16 + lr) << 3) + r8) = pk;
  }
}

// ---------------- k_main: fused einsum + self-MLP ----------------
__global__ __launch_bounds__(256, 2) void k_main(
    const float* __restrict__ edge,
    const unsigned short* __restrict__ gxF,
    const float* __restrict__ x,
    const float* __restrict__ fw1,
    const float* __restrict__ fb1,
    const float* __restrict__ fw2,
    const float* __restrict__ fb2,
    float* __restrict__ out)
{
  // eT[buf][jj 0..31][ii 0..63]: stride 72 shorts, chunk swizzle (ii>>3)^(jj>>3).
  // gx B-fragments read straight from global in fragment order (coalesced 16B/lane).
  __shared__ short eT[2][32 * 72]; // 9 KB double-buffered edge^T tile
  __shared__ short bT[128 * 64];   // 16 KB (epilogue: fw2T)
  __shared__ short xs[32 * 64];    // 4 KB  (epilogue)
  __shared__ short w1T[64 * 64];   // 8 KB  (epilogue)
  __shared__ short h1s[32 * 64];   // 4 KB  (epilogue)   total ~41 KB

  const int t = threadIdx.x;
  const int batch = blockIdx.x & 7;   // XCD-pinned: each XCD sees one batch's gx (512 KB)
  const int j0 = (blockIdx.x >> 3) * 32;

  const int w = t >> 6, l = t & 63;   // wave w owns h-range [w*32, w*32+32), both j-halves
  const int lr = l & 15, q = l >> 4;

  // edge loader roles: 256 threads cover 64i x 32j fp32 tile, f32x8 each
  const int e_ii = t >> 2;          // 0..63
  const int e_cj = t & 3;           // 0..3  (8 j each)

  const float* ep = edge + (size_t)batch * 2048 * 2048 + (size_t)e_ii * 2048 + j0 + e_cj * 8;
  // fragment-order gx base: + w*2048 selects this wave's h-blocks, + l*8 the lane slot
  const unsigned short* gp = gxF + (size_t)batch * (128 * 2048) + w * 2048 + (size_t)l * 8;

  f32x4 acc[4];  // [jm][nf] flattened
#pragma unroll
  for (int i = 0; i < 4; ++i) acc[i] = (f32x4){0.f, 0.f, 0.f, 0.f};

  // ---- helpers (all indices static after unroll) ----
  auto lde = [&](int kk, f32x4 er[2]) {
    const float* p = ep + (size_t)kk * 64 * 2048;
    er[0] = *(const f32x4*)p;
    er[1] = *(const f32x4*)(p + 4);
  };
  auto ldg = [&](int kk, bf16x8 gf[4]) {  // 4 coalesced 16B/lane loads (1 KB/wave each)
    const unsigned short* p = gp + kk * 8192;
#pragma unroll
    for (int nf = 0; nf < 2; ++nf)
#pragma unroll
      for (int ks = 0; ks < 2; ++ks)
        gf[nf * 2 + ks] = *(const bf16x8*)(p + nf * 1024 + ks * 512);
  };
  auto st_e = [&](int buf, const f32x4 er[2]) {
#pragma unroll
    for (int u = 0; u < 8; ++u) {
      int jj = e_cj * 8 + u;
      float v = (u < 4) ? er[0][u & 3] : er[1][u & 3];
      eT[buf][jj * 72 + (((e_ii >> 3) ^ e_cj) << 3) + (e_ii & 7)] = (short)f2bf_trunc(v);
    }
  };
  auto comp = [&](int buf, const bf16x8 gf[4]) {
    __builtin_amdgcn_s_setprio(1);
#pragma unroll
    for (int ks = 0; ks < 2; ++ks) {
      const int c = ks * 4 + q;
      bf16x8 a[2];
#pragma unroll
      for (int jm = 0; jm < 2; ++jm) {
        int jj = jm * 16 + lr;
        a[jm] = *(const bf16x8*)(&eT[buf][jj * 72 + ((c ^ (jj >> 3)) << 3)]);
      }
#pragma unroll
      for (int jm = 0; jm < 2; ++jm)
#pragma unroll
        for (int nf = 0; nf < 2; ++nf)
          acc[jm * 2 + nf] = __builtin_amdgcn_mfma_f32_16x16x32_bf16(a[jm], gf[nf * 2 + ks],
                                                                    acc[jm * 2 + nf], 0, 0, 0);
    }
    __builtin_amdgcn_s_setprio(0);
  };

  // ---- main K loop: 32 steps, distance-4 edge prefetch (erA..D), distance-1 gx ----
  // step s: ldg(s+1 -> gf[(s+1)&1]); lde(s+4 -> er[s&3]); comp(eT[s&1], gf[s&1]);
  //         st_e(eT[(s+1)&1], er[(s+1)&3]); LBAR
  f32x4 erA[2], erB[2], erC[2], erD[2];
  bf16x8 gfA[4], gfB[4];

  lde(0, erA); lde(1, erB); lde(2, erC); lde(3, erD);
  ldg(0, gfA);
  st_e(0, erA);
  LBAR();              // gfA, erB..erD stay in flight across the barrier

#pragma unroll 1
  for (int mm = 0; mm < 7; ++mm) {
    const int s = mm * 4;
    ldg(s + 1, gfB); lde(s + 4, erA); comp(0, gfA); st_e(1, erB); LBAR();
    ldg(s + 2, gfA); lde(s + 5, erB); comp(1, gfB); st_e(0, erC); LBAR();
    ldg(s + 3, gfB); lde(s + 6, erC); comp(0, gfA); st_e(1, erD); LBAR();
    ldg(s + 4, gfA); lde(s + 7, erD); comp(1, gfB); st_e(0, erA); LBAR();
  }
  // steps 28..31 (no more lde; tiles 28..31 already in erA..erD)
  ldg(29, gfB); comp(0, gfA); st_e(1, erB); LBAR();
  ldg(30, gfA); comp(1, gfB); st_e(0, erC); LBAR();
  ldg(31, gfB); comp(0, gfA); st_e(1, erD); LBAR();
  comp(1, gfB);

  // ---- fused self-MLP epilogue: acc += relu(x_j @ fw1 + b1) @ fw2 + b2 ----
  for (int idx = t; idx < 64 * 64; idx += 256) {
    int k = idx >> 6, n = idx & 63;  // fw1[k][n]
    w1T[(n << 6) + (((k >> 3) ^ (n & 7)) << 3) + (k & 7)] = (short)f2bf(fw1[idx]);
  }
  for (int idx = t; idx < 64 * 128; idx += 256) {
    int k = idx >> 7, n = idx & 127;  // fw2[k][n] -> bT as fw2T
    bT[(n << 6) + (((k >> 3) ^ (n & 7)) << 3) + (k & 7)] = (short)f2bf(fw2[idx]);
  }
  for (int s = t; s < 32 * 16; s += 256) {
    int row = s >> 4, c4 = s & 15;
    f32x4 v = *(const f32x4*)(x + (size_t)(batch * 2048 + j0 + row) * 64 + c4 * 4);
    u16x4 pk;
#pragma unroll
    for (int r = 0; r < 4; ++r) pk[r] = f2bf(v[r]);
    *(u16x4*)(xs + (row << 6) + (((c4 >> 1) ^ (row & 7)) << 3) + ((c4 & 1) << 2)) = pk;
  }
  __syncthreads();

  if (w < 2) {  // layer 1: waves 0,1 compute hidden[32][64]
    const int mrow = w * 16 + lr;
    bf16x8 a1[2];
#pragma unroll
    for (int ks = 0; ks < 2; ++ks) {
      int c = ks * 4 + q;
      a1[ks] = *(const bf16x8*)(xs + (mrow << 6) + ((c ^ (mrow & 7)) << 3));
    }
#pragma unroll
    for (int nf = 0; nf < 4; ++nf) {
      f32x4 h = (f32x4){0.f, 0.f, 0.f, 0.f};
#pragma unroll
      for (int ks = 0; ks < 2; ++ks) {
        int c = ks * 4 + q;
        int nr = nf * 16 + lr;
        bf16x8 b = *(const bf16x8*)(w1T + (nr << 6) + ((c ^ (nr & 7)) << 3));
        h = __builtin_amdgcn_mfma_f32_16x16x32_bf16(a1[ks], b, h, 0, 0, 0);
      }
      float bias = fb1[nf * 16 + lr];
#pragma unroll
      for (int r = 0; r < 4; ++r) {
        float v = h[r] + bias;
        v = v > 0.f ? v : 0.f;
        int row = w * 16 + q * 4 + r, n = nf * 16 + lr;
        h1s[(row << 6) + (((n >> 3) ^ (row & 7)) << 3) + (n & 7)] = (short)f2bf(v);
      }
    }
  }
  __syncthreads();

  // layer 2: all waves, accumulate straight into einsum acc
  bf16x8 a2[2][2];  // [jm][ks]
#pragma unroll
  for (int jm = 0; jm < 2; ++jm)
#pragma unroll
    for (int ks = 0; ks < 2; ++ks) {
      int c = ks * 4 + q;
      int mrow = jm * 16 + lr;
      a2[jm][ks] = *(const bf16x8*)(h1s + (mrow << 6) + ((c ^ (mrow & 7)) << 3));
    }
#pragma unroll
  for (int jm = 0; jm < 2; ++jm)
#pragma unroll
    for (int nf = 0; nf < 2; ++nf) {
      int h = w * 32 + nf * 16 + lr;
#pragma unroll
      for (int ks = 0; ks < 2; ++ks) {
        int c = ks * 4 + q;
        bf16x8 b = *(const bf16x8*)(bT + (h << 6) + ((c ^ (h & 7)) << 3));
        acc[jm * 2 + nf] = __builtin_amdgcn_mfma_f32_16x16x32_bf16(a2[jm][ks], b,
                                                                  acc[jm * 2 + nf], 0, 0, 0);
      }
      float bias = fb2[h];
#pragma unroll
      for (int r = 0; r < 4; ++r) {
        size_t o = ((size_t)batch * 2048 + j0 + jm * 16 + q * 4 + r) * 128 + h;
        out[o] = acc[jm * 2 + nf][r] + bias;
      }
    }
}

extern "C" void kernel_launch(void* const* d_in, const int* in_sizes, int n_in,
                              void* d_out, int out_size, void* d_ws, size_t ws_size,
                              hipStream_t stream) {
  const float* x    = (const float*)d_in[0];
  const float* edge = (const float*)d_in[1];
  const float* fw1  = (const float*)d_in[2];
  const float* fb1  = (const float*)d_in[3];
  const float* fw2  = (const float*)d_in[4];
  const float* fb2  = (const float*)d_in[5];
  const float* gw1  = (const float*)d_in[6];
  const float* gb1  = (const float*)d_in[7];
  const float* gw2  = (const float*)d_in[8];
  const float* gb2  = (const float*)d_in[9];
  float* out = (float*)d_out;

  unsigned short* gxF = (unsigned short*)d_ws;  // [8][32][8][2][64][8] bf16, 4 MB

  hipLaunchKernelGGL(k_gx, dim3(256), dim3(256), 0, stream, x, gw1, gb1, gw2, gb2, gxF);
  hipLaunchKernelGGL(k_main, dim3(512), dim3(256), 0, stream, edge, gxF, x,
                     fw1, fb1, fw2, fb2, out);
}